// Round 2
// baseline (16104.820 us; speedup 1.0000x reference)
//
#include <hip/hip_runtime.h>
#include <hip/hip_bf16.h>

#define B_ 128
#define T_ 1024
#define I_ 512
#define H_ 1024
#define O_ 512
#define NBLK 256

typedef __attribute__((ext_vector_type(8))) short bf16x8;
typedef __attribute__((ext_vector_type(4))) float f32x4;
typedef unsigned short u16;

__device__ __forceinline__ unsigned f2bf_u(float f) {
  union { float f; unsigned u; } v; v.f = f;
  return (v.u + 0x7fffu + ((v.u >> 16) & 1u)) >> 16;  // RNE bf16
}

__device__ __forceinline__ bf16x8 cvt8(const float* __restrict__ p) {
  union { bf16x8 v; unsigned u[4]; } r;
  const float4 f0 = *(const float4*)p;
  const float4 f1 = *(const float4*)(p + 4);
  r.u[0] = f2bf_u(f0.x) | (f2bf_u(f0.y) << 16);
  r.u[1] = f2bf_u(f0.z) | (f2bf_u(f0.w) << 16);
  r.u[2] = f2bf_u(f1.x) | (f2bf_u(f1.y) << 16);
  r.u[3] = f2bf_u(f1.z) | (f2bf_u(f1.w) << 16);
  return r.v;
}

// Persistent RNN kernel. 256 blocks x 256 threads (4 waves).
// Block (bm,bn): rows r0=bm*32 (batch), cols c0=bn*16 (hidden units).
// Waves K-split: wave w covers h-K [w*256,+256) and x-K [w*128,+128).
// W tile (16 cols x 1536 K, bf16) lives in LDS for the whole run.
__global__ __launch_bounds__(256) void rnn_persist(
    const float* __restrict__ x, const float* __restrict__ Wih,
    const float* __restrict__ bih, const float* __restrict__ Whh,
    const float* __restrict__ bhh, const float* __restrict__ Who,
    const float* __restrict__ bho, u16* __restrict__ h0buf,
    u16* __restrict__ h1buf, float* __restrict__ out,
    unsigned* __restrict__ cnt) {
  __shared__ u16 w_lds[192 * 16 * 8];   // 48 KB: [octet o][col c][8 bf16]
  __shared__ float red[256 * 12];       // 12 KB: K-split reduce, stride 12 dw
  __shared__ float bias_lds[16];

  const int tid = threadIdx.x;
  const int w = tid >> 6;
  const int lane = tid & 63;
  const int lr = lane & 15;   // fragment row/col
  const int kg = lane >> 4;   // k-octet group
  const int r0 = (blockIdx.x & 3) * 32;
  const int c0 = (blockIdx.x >> 2) * 16;

  // ---- stage W tile into LDS (once), interleaved [o][c] so a wave's
  // ds_read_b128s form one contiguous 1 KB block (conflict-free) ----
  for (int idx = tid; idx < 192 * 16; idx += 256) {
    int o = idx >> 4, c = idx & 15;
    int k = o * 8, gc = c0 + c;
    const float* src = (k < H_) ? (Whh + (size_t)gc * H_ + k)
                                : (Wih + (size_t)gc * I_ + (k - H_));
    *(bf16x8*)&w_lds[idx * 8] = cvt8(src);
  }
  if (tid < 16) bias_lds[tid] = bih[c0 + tid] + bhh[c0 + tid];
  __syncthreads();

  const int redbase = (w * 64 + lane) * 12;
  // reduce/store thread mapping: thread -> (row rr, col pair cp)
  const int rr = tid >> 3;
  const int cp = (tid & 7) * 2;
  const int lane_a = ((rr >> 2) & 3) << 4;
  const int jj = ((rr >> 4) << 2) + (rr & 3);

  const f32x4 zero4 = {0.f, 0.f, 0.f, 0.f};
  f32x4 acc0 = zero4, acc1 = zero4;

  // ---- x-part prologue for t=0 ----
  {
    const float* px0 = x + ((size_t)(r0 + lr) * T_ + 0) * I_ + w * 128 + kg * 8;
    const float* px1 = px0 + (size_t)16 * T_ * I_;
    const u16* wb = &w_lds[((128 + w * 16 + kg) * 16 + lr) * 8];
#pragma unroll
    for (int k0 = 0; k0 < 128; k0 += 32) {
      bf16x8 a0 = cvt8(px0 + k0);
      bf16x8 a1 = cvt8(px1 + k0);
      bf16x8 b = *(const bf16x8*)(wb + (k0 >> 3) * 128);
      acc0 = __builtin_amdgcn_mfma_f32_16x16x32_bf16(a0, b, acc0, 0, 0, 0);
      acc1 = __builtin_amdgcn_mfma_f32_16x16x32_bf16(a1, b, acc1, 0, 0, 0);
    }
  }

  for (int t = 0; t < T_; ++t) {
    const u16* hc = (t & 1) ? h1buf : h0buf;
    u16* hn = (t & 1) ? h0buf : h1buf;

    // ---- h-part: acc += h_t[32 rows, K-slice] @ W_hh^T ----
    if (t > 0) {
      const u16* pa0 = hc + (size_t)(r0 + lr) * H_ + w * 256 + kg * 8;
      const u16* pa1 = pa0 + 16 * H_;
      const u16* wb = &w_lds[((w * 32 + kg) * 16 + lr) * 8];
#pragma unroll
      for (int k0 = 0; k0 < 256; k0 += 32) {
        bf16x8 a0 = *(const bf16x8*)(pa0 + k0);
        bf16x8 a1 = *(const bf16x8*)(pa1 + k0);
        bf16x8 b = *(const bf16x8*)(wb + (k0 >> 3) * 128);
        acc0 = __builtin_amdgcn_mfma_f32_16x16x32_bf16(a0, b, acc0, 0, 0, 0);
        acc1 = __builtin_amdgcn_mfma_f32_16x16x32_bf16(a1, b, acc1, 0, 0, 0);
      }
    }

    // ---- 4-way K-reduce via LDS, bias+relu, pack+store h_{t+1} tile ----
    *(f32x4*)&red[redbase] = acc0;
    *(f32x4*)&red[redbase + 4] = acc1;
    __syncthreads();
    {
      float v0 = 0.f, v1 = 0.f;
#pragma unroll
      for (int ww = 0; ww < 4; ++ww) {
        v0 += red[(ww * 64 + lane_a + cp) * 12 + jj];
        v1 += red[(ww * 64 + lane_a + cp + 1) * 12 + jj];
      }
      v0 += bias_lds[cp];
      v1 += bias_lds[cp + 1];
      v0 = v0 > 0.f ? v0 : 0.f;
      v1 = v1 > 0.f ? v1 : 0.f;
      unsigned pk = f2bf_u(v0) | (f2bf_u(v1) << 16);
      *(unsigned*)(hn + (size_t)(r0 + rr) * H_ + c0 + cp) = pk;
    }
    __syncthreads();

    // ---- barrier arrive (release) ----
    if (tid == 0) {
      __threadfence();
      __hip_atomic_fetch_add(cnt, 1u, __ATOMIC_RELAXED, __HIP_MEMORY_SCOPE_AGENT);
    }

    // ---- x-part for t+1 (h-independent): hides under barrier wait ----
    acc0 = zero4;
    acc1 = zero4;
    if (t + 1 < T_) {
      const float* px0 =
          x + ((size_t)(r0 + lr) * T_ + (t + 1)) * I_ + w * 128 + kg * 8;
      const float* px1 = px0 + (size_t)16 * T_ * I_;
      const u16* wb = &w_lds[((128 + w * 16 + kg) * 16 + lr) * 8];
#pragma unroll
      for (int k0 = 0; k0 < 128; k0 += 32) {
        bf16x8 a0 = cvt8(px0 + k0);
        bf16x8 a1 = cvt8(px1 + k0);
        bf16x8 b = *(const bf16x8*)(wb + (k0 >> 3) * 128);
        acc0 = __builtin_amdgcn_mfma_f32_16x16x32_bf16(a0, b, acc0, 0, 0, 0);
        acc1 = __builtin_amdgcn_mfma_f32_16x16x32_bf16(a1, b, acc1, 0, 0, 0);
      }
    }

    // ---- barrier wait (acquire) ----
    if (tid == 0) {
      unsigned target = (unsigned)NBLK * (unsigned)(t + 1);
      while (__hip_atomic_load(cnt, __ATOMIC_RELAXED, __HIP_MEMORY_SCOPE_AGENT) <
             target)
        __builtin_amdgcn_s_sleep(2);
      __threadfence();
    }
    __syncthreads();
  }

  // ---- output GEMM: out = h_final @ W_ho^T + b_ho (final h in h0buf) ----
  if (blockIdx.x < 128) {
    const int r0o = (blockIdx.x & 3) * 32;
    const int c0o = (blockIdx.x >> 2) * 16;
    f32x4 o0 = zero4, o1 = zero4;
    const u16* pa0 = h0buf + (size_t)(r0o + lr) * H_ + w * 256 + kg * 8;
    const u16* pa1 = pa0 + 16 * H_;
    const float* pwo = Who + (size_t)(c0o + lr) * H_ + w * 256 + kg * 8;
#pragma unroll
    for (int k0 = 0; k0 < 256; k0 += 32) {
      bf16x8 a0 = *(const bf16x8*)(pa0 + k0);
      bf16x8 a1 = *(const bf16x8*)(pa1 + k0);
      bf16x8 b = cvt8(pwo + k0);
      o0 = __builtin_amdgcn_mfma_f32_16x16x32_bf16(a0, b, o0, 0, 0, 0);
      o1 = __builtin_amdgcn_mfma_f32_16x16x32_bf16(a1, b, o1, 0, 0, 0);
    }
    *(f32x4*)&red[redbase] = o0;
    *(f32x4*)&red[redbase + 4] = o1;
    __syncthreads();
    float v0 = 0.f, v1 = 0.f;
#pragma unroll
    for (int ww = 0; ww < 4; ++ww) {
      v0 += red[(ww * 64 + lane_a + cp) * 12 + jj];
      v1 += red[(ww * 64 + lane_a + cp + 1) * 12 + jj];
    }
    v0 += bho[c0o + cp];
    v1 += bho[c0o + cp + 1];
    float2 st = {v0, v1};
    *(float2*)(out + (size_t)(r0o + rr) * O_ + c0o + cp) = st;
  }
}

extern "C" void kernel_launch(void* const* d_in, const int* in_sizes, int n_in,
                              void* d_out, int out_size, void* d_ws,
                              size_t ws_size, hipStream_t stream) {
  const float* x = (const float*)d_in[0];
  const float* Wih = (const float*)d_in[1];
  const float* bih = (const float*)d_in[2];
  const float* Whh = (const float*)d_in[3];
  const float* bhh = (const float*)d_in[4];
  const float* Who = (const float*)d_in[5];
  const float* bho = (const float*)d_in[6];
  float* outp = (float*)d_out;

  char* ws = (char*)d_ws;
  unsigned* cnt = (unsigned*)ws;                       // [0,4)
  u16* h0b = (u16*)(ws + 1024);                        // 256 KB
  u16* h1b = (u16*)(ws + 1024 + B_ * H_ * 2);          // 256 KB

  hipMemsetAsync(cnt, 0, sizeof(unsigned), stream);

  void* args[] = {(void*)&x,   (void*)&Wih, (void*)&bih, (void*)&Whh,
                  (void*)&bhh, (void*)&Who, (void*)&bho, (void*)&h0b,
                  (void*)&h1b, (void*)&outp, (void*)&cnt};
  hipLaunchCooperativeKernel((void*)rnn_persist, dim3(NBLK), dim3(256), args, 0,
                             stream);
}